// Round 1
// baseline (2198.005 us; speedup 1.0000x reference)
//
#include <hip/hip_runtime.h>
#include <math.h>

#define N_ATOMS 3072
#define C_Ac 128
#define C_Sc 384
#define C_Zc 16

__device__ __forceinline__ float sigm(float x){ return 1.f/(1.f+__expf(-x)); }

// block-wide sum of two values across 256 threads (4 waves)
__device__ __forceinline__ void block_sum2(float& x, float& y, float* red){
  #pragma unroll
  for (int off=32; off; off>>=1){ x += __shfl_down(x,off,64); y += __shfl_down(y,off,64); }
  int tid = threadIdx.x;
  __syncthreads();               // protect red from previous use
  if ((tid&63)==0){ red[(tid>>6)*2]=x; red[(tid>>6)*2+1]=y; }
  __syncthreads();
  x = red[0]+red[2]+red[4]+red[6];
  y = red[1]+red[3]+red[5]+red[7];
}

// ---------------- Stage A: AdaLN1 + QKV/G projections ----------------
__global__ __launch_bounds__(256) void k_stage_a(
    const float* __restrict__ a, const float* __restrict__ s,
    const float* __restrict__ s_w, const float* __restrict__ scale_w,
    const float* __restrict__ scale_b, const float* __restrict__ shift_w,
    const float* __restrict__ wq, const float* __restrict__ bq,
    const float* __restrict__ wk, const float* __restrict__ wv,
    const float* __restrict__ wg,
    float* __restrict__ qo, float* __restrict__ ko, float* __restrict__ vo,
    float* __restrict__ go, float* __restrict__ lns)
{
  __shared__ float sn[C_Sc];
  __shared__ float an[C_Ac];
  __shared__ float h[C_Ac];
  __shared__ float red[8];
  int n = blockIdx.x; int tid = threadIdx.x;
  const float* srow = s + (size_t)n*C_Sc;

  float sx=0.f, sxx=0.f;
  for (int i=tid;i<C_Sc;i+=256){ float v=srow[i]; sx+=v; sxx+=v*v; }
  block_sum2(sx,sxx,red);
  float mean = sx*(1.f/C_Sc);
  float rs = rsqrtf(sxx*(1.f/C_Sc)-mean*mean+1e-5f);
  for (int i=tid;i<C_Sc;i+=256){
    float v=(srow[i]-mean)*rs;
    lns[(size_t)n*C_Sc+i]=v;           // cache LN(s) for stage C
    sn[i]=v*s_w[i];
  }

  const float* arow = a + (size_t)n*C_Ac;
  float ax=0.f, axx=0.f;
  for (int i=tid;i<C_Ac;i+=256){ float v=arow[i]; ax+=v; axx+=v*v; }
  block_sum2(ax,axx,red);
  mean = ax*(1.f/C_Ac);
  rs = rsqrtf(axx*(1.f/C_Ac)-mean*mean+1e-5f);
  for (int i=tid;i<C_Ac;i+=256) an[i]=(arow[i]-mean)*rs;
  __syncthreads();

  if (tid<C_Ac){
    int c=tid;
    float a1=scale_b[c], a2=0.f;
    for (int i=0;i<C_Sc;i++){ float sv=sn[i]; a1 += sv*scale_w[i*C_Ac+c]; a2 += sv*shift_w[i*C_Ac+c]; }
    h[c] = sigm(a1)*an[c] + a2;
  }
  __syncthreads();

  for (int o=tid;o<4*C_Ac;o+=256){
    int m=o>>7, c=o&127;
    const float* W = (m==0)?wq:(m==1)?wk:(m==2)?wv:wg;
    float acc = (m==0)?bq[c]:0.f;
    for (int i=0;i<C_Ac;i++) acc += h[i]*W[i*C_Ac+c];
    if (m==3) acc = sigm(acc);
    float* dst = (m==0)?qo:(m==1)?ko:(m==2)?vo:go;
    dst[(size_t)n*C_Ac+c]=acc;
  }
}

// ---------------- Stage B: pair-biased attention (fused z-LN bias) ----------------
__global__ __launch_bounds__(256) void k_attn(
    const float* __restrict__ z, const float* __restrict__ ln_z_w,
    const float* __restrict__ ln_z_b, const float* __restrict__ wb,
    const float* __restrict__ qws, const float* __restrict__ kws,
    const float* __restrict__ vws, const float* __restrict__ gws,
    float* __restrict__ gows)
{
  __shared__ float lzw[16], lzb[16], wbs[64];
  __shared__ float bias_l[4*256];
  __shared__ float o_part[32*257];
  __shared__ float l_part[256];
  int n = blockIdx.x; int tid = threadIdx.x;
  int w = tid>>6, lane = tid&63;
  if (tid<16){ lzw[tid]=ln_z_w[tid]; lzb[tid]=ln_z_b[tid]; }
  else if (tid>=64 && tid<128) wbs[tid-64]=wb[tid-64];
  __syncthreads();

  float qv[32];
  {
    const float4* qp = reinterpret_cast<const float4*>(qws + (size_t)n*C_Ac + w*32);
    #pragma unroll
    for (int j=0;j<8;j++){ float4 t=qp[j]; qv[4*j]=t.x; qv[4*j+1]=t.y; qv[4*j+2]=t.z; qv[4*j+3]=t.w; }
  }
  float m=-INFINITY, l=0.f, o[32];
  #pragma unroll
  for (int j=0;j<32;j++) o[j]=0.f;
  const float inv_sqrt_d = 0.17677669529663687f;

  for (int tile=0; tile<N_ATOMS/256; tile++){
    { // all 256 threads: bias for this key tile (z read once, all 4 heads)
      int kk = tile*256 + tid;
      const float4* zp = reinterpret_cast<const float4*>(z + ((size_t)n*N_ATOMS + kk)*C_Zc);
      float zv[16];
      #pragma unroll
      for (int j=0;j<4;j++){ float4 t=zp[j]; zv[4*j]=t.x; zv[4*j+1]=t.y; zv[4*j+2]=t.z; zv[4*j+3]=t.w; }
      float sum=0.f, ssq=0.f;
      #pragma unroll
      for (int c=0;c<16;c++){ sum+=zv[c]; ssq+=zv[c]*zv[c]; }
      float mz = sum*(1.f/16);
      float rz = rsqrtf(ssq*(1.f/16)-mz*mz+1e-5f);
      float b0=0.f,b1=0.f,b2=0.f,b3=0.f;
      #pragma unroll
      for (int c=0;c<16;c++){
        float znv = (zv[c]-mz)*rz*lzw[c]+lzb[c];
        b0+=znv*wbs[c*4]; b1+=znv*wbs[c*4+1]; b2+=znv*wbs[c*4+2]; b3+=znv*wbs[c*4+3];
      }
      bias_l[0*256+tid]=b0; bias_l[1*256+tid]=b1; bias_l[2*256+tid]=b2; bias_l[3*256+tid]=b3;
    }
    __syncthreads();
    for (int i=0;i<4;i++){
      int key = tile*256 + i*64 + lane;
      const float4* kp = reinterpret_cast<const float4*>(kws + (size_t)key*C_Ac + w*32);
      float dot=0.f;
      #pragma unroll
      for (int j=0;j<8;j++){ float4 t=kp[j]; dot += qv[4*j]*t.x+qv[4*j+1]*t.y+qv[4*j+2]*t.z+qv[4*j+3]*t.w; }
      float logit = dot*inv_sqrt_d + bias_l[w*256 + i*64 + lane];
      float mn = fmaxf(m, logit);
      float ef = __expf(m-mn), ev = __expf(logit-mn);
      l = l*ef + ev;
      const float4* vp = reinterpret_cast<const float4*>(vws + (size_t)key*C_Ac + w*32);
      #pragma unroll
      for (int j=0;j<8;j++){ float4 t=vp[j];
        o[4*j]  =o[4*j]  *ef+ev*t.x; o[4*j+1]=o[4*j+1]*ef+ev*t.y;
        o[4*j+2]=o[4*j+2]*ef+ev*t.z; o[4*j+3]=o[4*j+3]*ef+ev*t.w; }
      m = mn;
    }
    __syncthreads();   // bias LDS reused next tile
  }

  // combine 64 lanes' online-softmax states per wave (per head)
  float gm = m;
  #pragma unroll
  for (int off=32; off; off>>=1) gm = fmaxf(gm, __shfl_xor(gm, off, 64));
  float sc = __expf(m-gm);
  l_part[w*64+lane] = l*sc;
  #pragma unroll
  for (int j=0;j<32;j++) o_part[j*257 + w*64 + lane] = o[j]*sc;
  __syncthreads();
  if (tid<128){
    int hh=tid>>5, d=tid&31;
    float osum=0.f, lsum=0.f;
    for (int ln2=0;ln2<64;ln2++){
      osum += o_part[d*257 + hh*64 + ln2];
      lsum += l_part[hh*64 + ln2];
    }
    // g (already sigmoided) * normalized o; channel c == tid (head-major)
    gows[(size_t)n*C_Ac + tid] = gws[(size_t)n*C_Ac + tid] * (osum/lsum);
  }
}

// ---------------- Stage C: out-proj + gate + residual + conditioned transition ----------------
__global__ __launch_bounds__(256) void k_stage_c(
    const float* __restrict__ gows, const float* __restrict__ wo,
    const float* __restrict__ s, const float* __restrict__ sgate1_w,
    const float* __restrict__ sgate1_b, const float* __restrict__ a,
    const float* __restrict__ lns, const float* __restrict__ s_w2,
    const float* __restrict__ scale_w2, const float* __restrict__ scale_b2,
    const float* __restrict__ shift_w2, const float* __restrict__ w1,
    const float* __restrict__ w2, const float* __restrict__ wout,
    const float* __restrict__ sgate2_w, const float* __restrict__ sgate2_b,
    float* __restrict__ out)
{
  __shared__ float srow[C_Sc], sn2[C_Sc], gor[C_Ac], ats[C_Ac], h2[C_Ac], gated[2*C_Ac];
  __shared__ float red[8];
  int n=blockIdx.x, tid=threadIdx.x;
  for (int i=tid;i<C_Sc;i+=256){
    srow[i]=s[(size_t)n*C_Sc+i];
    sn2[i]=lns[(size_t)n*C_Sc+i]*s_w2[i];
  }
  for (int i=tid;i<C_Ac;i+=256) gor[i]=gows[(size_t)n*C_Ac+i];
  __syncthreads();

  if (tid<C_Ac){
    int c=tid;
    float x=0.f;
    for (int i=0;i<C_Ac;i++) x += gor[i]*wo[i*C_Ac+c];
    float sg=sgate1_b[c];
    for (int i=0;i<C_Sc;i++) sg += srow[i]*sgate1_w[i*C_Ac+c];
    ats[c] = sigm(sg)*x + a[(size_t)n*C_Ac+c];   // residual 1
  }
  __syncthreads();

  float ax=0.f, axx=0.f;
  for (int i=tid;i<C_Ac;i+=256){ float v=ats[i]; ax+=v; axx+=v*v; }
  block_sum2(ax,axx,red);
  float mean = ax*(1.f/C_Ac);
  float rs = rsqrtf(axx*(1.f/C_Ac)-mean*mean+1e-5f);
  if (tid<C_Ac){
    int c=tid;
    float anv=(ats[c]-mean)*rs;
    float a1=scale_b2[c], a2=0.f;
    for (int i=0;i<C_Sc;i++){ float sv=sn2[i]; a1+=sv*scale_w2[i*C_Ac+c]; a2+=sv*shift_w2[i*C_Ac+c]; }
    h2[c]=sigm(a1)*anv+a2;
  }
  __syncthreads();

  { // SwiGLU hidden, 256 outputs, one per thread
    float a1=0.f,a2=0.f;
    for (int i=0;i<C_Ac;i++){ float hv=h2[i]; a1+=hv*w1[i*2*C_Ac+tid]; a2+=hv*w2[i*2*C_Ac+tid]; }
    gated[tid] = a1*sigm(a1)*a2;   // silu(b1)*b2
  }
  __syncthreads();

  if (tid<C_Ac){
    int c=tid;
    float ff=0.f;
    for (int j=0;j<2*C_Ac;j++) ff += gated[j]*wout[j*C_Ac+c];
    float sg=sgate2_b[c];
    for (int i=0;i<C_Sc;i++) sg += srow[i]*sgate2_w[i*C_Ac+c];
    out[(size_t)n*C_Ac+c] = sigm(sg)*ff + ats[c];   // residual 2
  }
}

extern "C" void kernel_launch(void* const* d_in, const int* in_sizes, int n_in,
                              void* d_out, int out_size, void* d_ws, size_t ws_size,
                              hipStream_t stream)
{
  const float* a            = (const float*)d_in[0];
  const float* s            = (const float*)d_in[1];
  const float* z            = (const float*)d_in[2];
  const float* aln1_s_w     = (const float*)d_in[3];
  const float* aln1_scale_w = (const float*)d_in[4];
  const float* aln1_scale_b = (const float*)d_in[5];
  const float* aln1_shift_w = (const float*)d_in[6];
  const float* wq           = (const float*)d_in[7];
  const float* bq           = (const float*)d_in[8];
  const float* wk           = (const float*)d_in[9];
  const float* wv           = (const float*)d_in[10];
  const float* ln_z_w       = (const float*)d_in[11];
  const float* ln_z_b       = (const float*)d_in[12];
  const float* wb           = (const float*)d_in[13];
  const float* wg           = (const float*)d_in[14];
  const float* wo           = (const float*)d_in[15];
  const float* sgate1_w     = (const float*)d_in[16];
  const float* sgate1_b     = (const float*)d_in[17];
  const float* aln2_s_w     = (const float*)d_in[18];
  const float* aln2_scale_w = (const float*)d_in[19];
  const float* aln2_scale_b = (const float*)d_in[20];
  const float* aln2_shift_w = (const float*)d_in[21];
  const float* w1           = (const float*)d_in[22];
  const float* w2           = (const float*)d_in[23];
  const float* wout         = (const float*)d_in[24];
  const float* sgate2_w     = (const float*)d_in[25];
  const float* sgate2_b     = (const float*)d_in[26];
  float* out = (float*)d_out;

  float* ws  = (float*)d_ws;
  float* qws = ws;
  float* kws = qws + (size_t)N_ATOMS*C_Ac;
  float* vws = kws + (size_t)N_ATOMS*C_Ac;
  float* gws = vws + (size_t)N_ATOMS*C_Ac;
  float* gows= gws + (size_t)N_ATOMS*C_Ac;
  float* lns = gows+ (size_t)N_ATOMS*C_Ac;   // N*C_S floats

  hipLaunchKernelGGL(k_stage_a, dim3(N_ATOMS), dim3(256), 0, stream,
      a, s, aln1_s_w, aln1_scale_w, aln1_scale_b, aln1_shift_w,
      wq, bq, wk, wv, wg, qws, kws, vws, gws, lns);
  hipLaunchKernelGGL(k_attn, dim3(N_ATOMS), dim3(256), 0, stream,
      z, ln_z_w, ln_z_b, wb, qws, kws, vws, gws, gows);
  hipLaunchKernelGGL(k_stage_c, dim3(N_ATOMS), dim3(256), 0, stream,
      gows, wo, s, sgate1_w, sgate1_b, a, lns, aln2_s_w,
      aln2_scale_w, aln2_scale_b, aln2_shift_w, w1, w2, wout,
      sgate2_w, sgate2_b, out);
}

// Round 2
// 1197.204 us; speedup vs baseline: 1.8359x; 1.8359x over previous
//
#include <hip/hip_runtime.h>
#include <math.h>

#define N_ATOMS 3072
#define C_Ac 128
#define C_Sc 384
#define C_Zc 16
#define QT 64          // queries per attention block
#define KC 16          // k-chunks (flash-decoding splits)
#define CHUNK (N_ATOMS/KC)   // 192 keys per chunk
#define KT 16          // keys per sub-tile (bias staging)
#define NQT (N_ATOMS/QT)     // 48 q-tiles

__device__ __forceinline__ float sigm(float x){ return 1.f/(1.f+__expf(-x)); }

// ---------------- Stage A: AdaLN1 + QKV/G projections (4 rows/block) ----------------
__global__ __launch_bounds__(256) void k_stage_a(
    const float* __restrict__ a, const float* __restrict__ s,
    const float* __restrict__ s_w, const float* __restrict__ scale_w,
    const float* __restrict__ scale_b, const float* __restrict__ shift_w,
    const float* __restrict__ wq, const float* __restrict__ bq,
    const float* __restrict__ wk, const float* __restrict__ wv,
    const float* __restrict__ wg,
    float* __restrict__ qo, float* __restrict__ ko, float* __restrict__ vo,
    float* __restrict__ go, float* __restrict__ lns)
{
  __shared__ float sn[4][C_Sc];
  __shared__ float an[4][C_Ac];
  __shared__ float hsh[4][C_Ac];
  __shared__ float t1[4][C_Ac], t2[4][C_Ac];
  int n0 = blockIdx.x*4;
  int tid = threadIdx.x, w = tid>>6, lane = tid&63;

  { // LN(s), row = wave
    const float* srow = s + (size_t)(n0+w)*C_Sc;
    float v[6]; float sx=0.f, sxx=0.f;
    #pragma unroll
    for (int j=0;j<6;j++){ v[j]=srow[lane+j*64]; sx+=v[j]; sxx+=v[j]*v[j]; }
    #pragma unroll
    for (int off=32;off;off>>=1){ sx+=__shfl_xor(sx,off,64); sxx+=__shfl_xor(sxx,off,64); }
    float mean=sx*(1.f/C_Sc), rs=rsqrtf(sxx*(1.f/C_Sc)-mean*mean+1e-5f);
    #pragma unroll
    for (int j=0;j<6;j++){
      int i=lane+j*64;
      float ln=(v[j]-mean)*rs;
      lns[(size_t)(n0+w)*C_Sc+i]=ln;
      sn[w][i]=ln*s_w[i];
    }
  }
  { // LN(a), row = wave
    const float* arow = a + (size_t)(n0+w)*C_Ac;
    float v0=arow[lane], v1=arow[lane+64];
    float sx=v0+v1, sxx=v0*v0+v1*v1;
    #pragma unroll
    for (int off=32;off;off>>=1){ sx+=__shfl_xor(sx,off,64); sxx+=__shfl_xor(sxx,off,64); }
    float mean=sx*(1.f/C_Ac), rs=rsqrtf(sxx*(1.f/C_Ac)-mean*mean+1e-5f);
    an[w][lane]=(v0-mean)*rs; an[w][lane+64]=(v1-mean)*rs;
  }
  __syncthreads();

  { // AdaLN1 matmuls: sel0 -> sigmoid(scale), sel1 -> shift
    int c = tid&127, sel = tid>>7;
    const float* W = sel ? shift_w : scale_w;
    float acc[4];
    #pragma unroll
    for (int r=0;r<4;r++) acc[r] = sel ? 0.f : scale_b[c];
    for (int i=0;i<C_Sc;i++){
      float wv = W[(size_t)i*C_Ac+c];
      #pragma unroll
      for (int r=0;r<4;r++) acc[r] += sn[r][i]*wv;
    }
    if (sel==0){ t1[0][c]=sigm(acc[0]); t1[1][c]=sigm(acc[1]); t1[2][c]=sigm(acc[2]); t1[3][c]=sigm(acc[3]); }
    else       { t2[0][c]=acc[0]; t2[1][c]=acc[1]; t2[2][c]=acc[2]; t2[3][c]=acc[3]; }
  }
  __syncthreads();
  for (int f=tid; f<512; f+=256){ int r=f>>7, c=f&127; hsh[r][c] = t1[r][c]*an[r][c] + t2[r][c]; }
  __syncthreads();

  { // QKVG: sel0 -> (q,k), sel1 -> (v,g)
    int c = tid&127, sel = tid>>7;
    const float* Wa = sel ? wv : wq;
    const float* Wb = sel ? wg : wk;
    float accA[4], accB[4];
    #pragma unroll
    for (int r=0;r<4;r++){ accA[r] = sel ? 0.f : bq[c]; accB[r]=0.f; }
    for (int i=0;i<C_Ac;i++){
      float wa=Wa[(size_t)i*C_Ac+c], wb_=Wb[(size_t)i*C_Ac+c];
      #pragma unroll
      for (int r=0;r<4;r++){ float hv=hsh[r][i]; accA[r]+=hv*wa; accB[r]+=hv*wb_; }
    }
    #pragma unroll
    for (int r=0;r<4;r++){
      size_t idx = (size_t)(n0+r)*C_Ac + c;
      if (sel==0){ qo[idx]=accA[r]; ko[idx]=accB[r]; }
      else       { vo[idx]=accA[r]; go[idx]=sigm(accB[r]); }
    }
  }
}

// ---------------- Stage B: flash-decoding attention with fused z bias ----------------
__global__ __launch_bounds__(256) void k_attn(
    const float* __restrict__ z, const float* __restrict__ ln_z_w,
    const float* __restrict__ ln_z_b, const float* __restrict__ wb,
    const float* __restrict__ qws, const float* __restrict__ kws,
    const float* __restrict__ vws,
    float* __restrict__ part_m, float* __restrict__ part_l,
    float* __restrict__ part_o)
{
  __shared__ float bias[4][QT][KT+1];
  __shared__ float lzw[16], lzb[16], wbs[64];
  int qt = blockIdx.x, chunk = blockIdx.y;
  int q0 = qt*QT, k_base = chunk*CHUNK;
  int tid = threadIdx.x, w = tid>>6, lane = tid&63;
  int wh = __builtin_amdgcn_readfirstlane(w);
  if (tid<16){ lzw[tid]=ln_z_w[tid]; lzb[tid]=ln_z_b[tid]; }
  else if (tid>=64 && tid<128) wbs[tid-64]=wb[tid-64];

  float qv[32];
  {
    const float4* qp = (const float4*)(qws + (size_t)(q0+lane)*C_Ac + wh*32);
    #pragma unroll
    for (int j=0;j<8;j++){ float4 t=qp[j]; qv[4*j]=t.x; qv[4*j+1]=t.y; qv[4*j+2]=t.z; qv[4*j+3]=t.w; }
  }
  float m=-INFINITY, l=0.f, o[32];
  #pragma unroll
  for (int j=0;j<32;j++) o[j]=0.f;
  const float isd = 0.17677669529663687f;

  for (int st=0; st<CHUNK/KT; st++){
    int k0 = k_base + st*KT;
    __syncthreads();     // previous sub-tile's bias reads done
    // bias phase: 64q x 16k pairs, 4 passes of 256 threads, coalesced z reads
    #pragma unroll
    for (int pass=0; pass<4; pass++){
      int ql = pass*16 + (tid>>4);
      int kl = tid&15;
      const float4* zp = (const float4*)(z + ((size_t)(q0+ql)*N_ATOMS + (k0+kl))*C_Zc);
      float zv[16];
      #pragma unroll
      for (int j=0;j<4;j++){ float4 t=zp[j]; zv[4*j]=t.x; zv[4*j+1]=t.y; zv[4*j+2]=t.z; zv[4*j+3]=t.w; }
      float sum=0.f, ssq=0.f;
      #pragma unroll
      for (int c=0;c<16;c++){ sum+=zv[c]; ssq+=zv[c]*zv[c]; }
      float mz=sum*(1.f/16), rz=rsqrtf(ssq*(1.f/16)-mz*mz+1e-5f);
      float b0=0.f,b1=0.f,b2=0.f,b3=0.f;
      #pragma unroll
      for (int c=0;c<16;c++){
        float znv=(zv[c]-mz)*rz*lzw[c]+lzb[c];
        b0+=znv*wbs[c*4]; b1+=znv*wbs[c*4+1]; b2+=znv*wbs[c*4+2]; b3+=znv*wbs[c*4+3];
      }
      bias[0][ql][kl]=b0; bias[1][ql][kl]=b1; bias[2][ql][kl]=b2; bias[3][ql][kl]=b3;
    }
    __syncthreads();
    // main: lane=q, K/V rows are wave-uniform (scalar/broadcast loads)
    for (int kl=0;kl<KT;kl++){
      const float4* kp = (const float4*)(kws + (size_t)(k0+kl)*C_Ac + wh*32);
      float dot=0.f;
      #pragma unroll
      for (int j=0;j<8;j++){ float4 t=kp[j]; dot += qv[4*j]*t.x+qv[4*j+1]*t.y+qv[4*j+2]*t.z+qv[4*j+3]*t.w; }
      float logit = dot*isd + bias[w][lane][kl];
      float mn = fmaxf(m, logit);
      float ef = __expf(m-mn), ev = __expf(logit-mn);
      l = l*ef + ev; m = mn;
      const float4* vp = (const float4*)(vws + (size_t)(k0+kl)*C_Ac + wh*32);
      #pragma unroll
      for (int j=0;j<8;j++){ float4 t=vp[j];
        o[4*j]  =o[4*j]  *ef+ev*t.x; o[4*j+1]=o[4*j+1]*ef+ev*t.y;
        o[4*j+2]=o[4*j+2]*ef+ev*t.z; o[4*j+3]=o[4*j+3]*ef+ev*t.w; }
    }
  }
  // write partials
  size_t pb = (((size_t)chunk*NQT + qt)*4 + w)*64 + lane;
  part_m[pb]=m; part_l[pb]=l;
  float4* po = (float4*)(part_o + pb*32);
  #pragma unroll
  for (int j=0;j<8;j++){ po[j] = make_float4(o[4*j],o[4*j+1],o[4*j+2],o[4*j+3]); }
}

// ---------------- Stage B2: combine partials + gate ----------------
__global__ __launch_bounds__(256) void k_combine(
    const float* __restrict__ part_m, const float* __restrict__ part_l,
    const float* __restrict__ part_o, const float* __restrict__ gws,
    float* __restrict__ gows)
{
  int qt = blockIdx.x, h = blockIdx.y;
  int tid = threadIdx.x, ql = tid&63, dg = tid>>6;
  float mc[KC], lc[KC], M=-INFINITY;
  #pragma unroll
  for (int c=0;c<KC;c++){
    size_t pb = (((size_t)c*NQT + qt)*4 + h)*64 + ql;
    mc[c]=part_m[pb]; lc[c]=part_l[pb]; M=fmaxf(M,mc[c]);
  }
  float L=0.f, oa[8];
  #pragma unroll
  for (int j=0;j<8;j++) oa[j]=0.f;
  #pragma unroll
  for (int c=0;c<KC;c++){
    float sc=__expf(mc[c]-M);
    L += lc[c]*sc;
    const float4* po = (const float4*)(part_o + ((((size_t)c*NQT + qt)*4 + h)*64 + ql)*32 + dg*8);
    float4 t0=po[0], t1=po[1];
    oa[0]+=sc*t0.x; oa[1]+=sc*t0.y; oa[2]+=sc*t0.z; oa[3]+=sc*t0.w;
    oa[4]+=sc*t1.x; oa[5]+=sc*t1.y; oa[6]+=sc*t1.z; oa[7]+=sc*t1.w;
  }
  float invL = 1.f/L;
  size_t base = (size_t)(qt*64+ql)*C_Ac + h*32 + dg*8;
  #pragma unroll
  for (int j=0;j<8;j++) gows[base+j] = gws[base+j]*oa[j]*invL;
}

// ---------------- Stage C: out-proj + gates + transition (4 rows/block) ----------------
__global__ __launch_bounds__(256) void k_stage_c(
    const float* __restrict__ gows, const float* __restrict__ wo,
    const float* __restrict__ s, const float* __restrict__ sgate1_w,
    const float* __restrict__ sgate1_b, const float* __restrict__ a,
    const float* __restrict__ lns, const float* __restrict__ s_w2,
    const float* __restrict__ scale_w2, const float* __restrict__ scale_b2,
    const float* __restrict__ shift_w2, const float* __restrict__ w1,
    const float* __restrict__ w2, const float* __restrict__ wout,
    const float* __restrict__ sgate2_w, const float* __restrict__ sgate2_b,
    float* __restrict__ out)
{
  __shared__ float srow[4][C_Sc], sn2[4][C_Sc];
  __shared__ float gor[4][C_Ac], ats[4][C_Ac], h2[4][C_Ac];
  __shared__ float gated[4][2*C_Ac];
  __shared__ float t1[4][C_Ac], t2[4][C_Ac], ta[4][C_Ac], tb[4][C_Ac];
  int n0 = blockIdx.x*4;
  int tid = threadIdx.x, w = tid>>6, lane = tid&63;

  for (int r=0;r<4;r++)
    for (int i=tid;i<C_Sc;i+=256){
      float sv = s[(size_t)(n0+r)*C_Sc+i];
      srow[r][i]=sv;
      sn2[r][i]=lns[(size_t)(n0+r)*C_Sc+i]*s_w2[i];
    }
  for (int f=tid; f<512; f+=256){ int r=f>>7, c=f&127; gor[r][c]=gows[(size_t)(n0+r)*C_Ac+c]; }
  __syncthreads();

  { // P1: sel0 -> out-proj x; sel1 -> sigmoid(s-gate1)
    int c = tid&127, sel = tid>>7;
    float acc[4];
    if (sel==0){
      #pragma unroll
      for (int r=0;r<4;r++) acc[r]=0.f;
      for (int i=0;i<C_Ac;i++){
        float wv=wo[(size_t)i*C_Ac+c];
        #pragma unroll
        for (int r=0;r<4;r++) acc[r]+=gor[r][i]*wv;
      }
      #pragma unroll
      for (int r=0;r<4;r++) t1[r][c]=acc[r];
    } else {
      #pragma unroll
      for (int r=0;r<4;r++) acc[r]=sgate1_b[c];
      for (int i=0;i<C_Sc;i++){
        float wv=sgate1_w[(size_t)i*C_Ac+c];
        #pragma unroll
        for (int r=0;r<4;r++) acc[r]+=srow[r][i]*wv;
      }
      #pragma unroll
      for (int r=0;r<4;r++) t2[r][c]=sigm(acc[r]);
    }
  }
  __syncthreads();
  for (int f=tid; f<512; f+=256){ int r=f>>7, c=f&127;
    ats[r][c] = t2[r][c]*t1[r][c] + a[(size_t)(n0+r)*C_Ac+c]; }
  __syncthreads();

  { // P2: LN(ats), row = wave; anv -> t1
    float v0=ats[w][lane], v1=ats[w][lane+64];
    float sx=v0+v1, sxx=v0*v0+v1*v1;
    #pragma unroll
    for (int off=32;off;off>>=1){ sx+=__shfl_xor(sx,off,64); sxx+=__shfl_xor(sxx,off,64); }
    float mean=sx*(1.f/C_Ac), rs=rsqrtf(sxx*(1.f/C_Ac)-mean*mean+1e-5f);
    t1[w][lane]=(v0-mean)*rs; t1[w][lane+64]=(v1-mean)*rs;
  }
  __syncthreads();

  { // P3: AdaLN2: sel0 -> ta = sigm(scale)*anv; sel1 -> tb = shift
    int c = tid&127, sel = tid>>7;
    float acc[4];
    const float* W = sel ? shift_w2 : scale_w2;
    #pragma unroll
    for (int r=0;r<4;r++) acc[r] = sel ? 0.f : scale_b2[c];
    for (int i=0;i<C_Sc;i++){
      float wv=W[(size_t)i*C_Ac+c];
      #pragma unroll
      for (int r=0;r<4;r++) acc[r]+=sn2[r][i]*wv;
    }
    if (sel==0){ 
      #pragma unroll
      for (int r=0;r<4;r++) ta[r][c]=sigm(acc[r])*t1[r][c];
    } else {
      #pragma unroll
      for (int r=0;r<4;r++) tb[r][c]=acc[r];
    }
  }
  __syncthreads();
  for (int f=tid; f<512; f+=256){ int r=f>>7, c=f&127; h2[r][c]=ta[r][c]+tb[r][c]; }
  __syncthreads();

  { // P4: SwiGLU hidden: thread owns col j of 256
    int j = tid;
    float a1[4], a2[4];
    #pragma unroll
    for (int r=0;r<4;r++){ a1[r]=0.f; a2[r]=0.f; }
    for (int i=0;i<C_Ac;i++){
      float w1v=w1[(size_t)i*2*C_Ac+j], w2v=w2[(size_t)i*2*C_Ac+j];
      #pragma unroll
      for (int r=0;r<4;r++){ float hv=h2[r][i]; a1[r]+=hv*w1v; a2[r]+=hv*w2v; }
    }
    #pragma unroll
    for (int r=0;r<4;r++) gated[r][j]=a1[r]*sigm(a1[r])*a2[r];
  }
  __syncthreads();

  { // P5: sel0 -> ff = gated@wout; sel1 -> sigmoid(s-gate2)
    int c = tid&127, sel = tid>>7;
    float acc[4];
    if (sel==0){
      #pragma unroll
      for (int r=0;r<4;r++) acc[r]=0.f;
      for (int j=0;j<2*C_Ac;j++){
        float wv=wout[(size_t)j*C_Ac+c];
        #pragma unroll
        for (int r=0;r<4;r++) acc[r]+=gated[r][j]*wv;
      }
      #pragma unroll
      for (int r=0;r<4;r++) t1[r][c]=acc[r];
    } else {
      #pragma unroll
      for (int r=0;r<4;r++) acc[r]=sgate2_b[c];
      for (int i=0;i<C_Sc;i++){
        float wv=sgate2_w[(size_t)i*C_Ac+c];
        #pragma unroll
        for (int r=0;r<4;r++) acc[r]+=srow[r][i]*wv;
      }
      #pragma unroll
      for (int r=0;r<4;r++) t2[r][c]=sigm(acc[r]);
    }
  }
  __syncthreads();
  for (int f=tid; f<512; f+=256){ int r=f>>7, c=f&127;
    out[(size_t)(n0+r)*C_Ac+c] = t2[r][c]*t1[r][c] + ats[r][c]; }
}

extern "C" void kernel_launch(void* const* d_in, const int* in_sizes, int n_in,
                              void* d_out, int out_size, void* d_ws, size_t ws_size,
                              hipStream_t stream)
{
  const float* a            = (const float*)d_in[0];
  const float* s            = (const float*)d_in[1];
  const float* z            = (const float*)d_in[2];
  const float* aln1_s_w     = (const float*)d_in[3];
  const float* aln1_scale_w = (const float*)d_in[4];
  const float* aln1_scale_b = (const float*)d_in[5];
  const float* aln1_shift_w = (const float*)d_in[6];
  const float* wq           = (const float*)d_in[7];
  const float* bq           = (const float*)d_in[8];
  const float* wk           = (const float*)d_in[9];
  const float* wv           = (const float*)d_in[10];
  const float* ln_z_w       = (const float*)d_in[11];
  const float* ln_z_b       = (const float*)d_in[12];
  const float* wb           = (const float*)d_in[13];
  const float* wg           = (const float*)d_in[14];
  const float* wo           = (const float*)d_in[15];
  const float* sgate1_w     = (const float*)d_in[16];
  const float* sgate1_b     = (const float*)d_in[17];
  const float* aln2_s_w     = (const float*)d_in[18];
  const float* aln2_scale_w = (const float*)d_in[19];
  const float* aln2_scale_b = (const float*)d_in[20];
  const float* aln2_shift_w = (const float*)d_in[21];
  const float* w1           = (const float*)d_in[22];
  const float* w2           = (const float*)d_in[23];
  const float* wout         = (const float*)d_in[24];
  const float* sgate2_w     = (const float*)d_in[25];
  const float* sgate2_b     = (const float*)d_in[26];
  float* out = (float*)d_out;

  float* ws   = (float*)d_ws;
  float* qws  = ws;                               // N*C_A
  float* kws  = qws  + (size_t)N_ATOMS*C_Ac;
  float* vws  = kws  + (size_t)N_ATOMS*C_Ac;
  float* gws  = vws  + (size_t)N_ATOMS*C_Ac;
  float* gows = gws  + (size_t)N_ATOMS*C_Ac;
  float* lns  = gows + (size_t)N_ATOMS*C_Ac;      // N*C_S
  float* part_m = lns + (size_t)N_ATOMS*C_Sc;     // KC*NQT*4*64
  float* part_l = part_m + (size_t)KC*NQT*4*64;
  float* part_o = part_l + (size_t)KC*NQT*4*64;   // KC*NQT*4*64*32

  hipLaunchKernelGGL(k_stage_a, dim3(N_ATOMS/4), dim3(256), 0, stream,
      a, s, aln1_s_w, aln1_scale_w, aln1_scale_b, aln1_shift_w,
      wq, bq, wk, wv, wg, qws, kws, vws, gws, lns);
  hipLaunchKernelGGL(k_attn, dim3(NQT, KC), dim3(256), 0, stream,
      z, ln_z_w, ln_z_b, wb, qws, kws, vws, part_m, part_l, part_o);
  hipLaunchKernelGGL(k_combine, dim3(NQT, 4), dim3(256), 0, stream,
      part_m, part_l, part_o, gws, gows);
  hipLaunchKernelGGL(k_stage_c, dim3(N_ATOMS/4), dim3(256), 0, stream,
      gows, wo, s, sgate1_w, sgate1_b, a, lns, aln2_s_w,
      aln2_scale_w, aln2_scale_b, aln2_shift_w, w1, w2, wout,
      sgate2_w, sgate2_b, out);
}